// Round 1
// baseline (858.645 us; speedup 1.0000x reference)
//
#include <hip/hip_runtime.h>
#include <math.h>

#define DIM 128
#define LN_EPS 1e-5f

// ---------------------------------------------------------------------------
// Kernel A: per-node LayerNorm fused with h = xn @ W^T
// block = 256 threads, 32 nodes per block.
// LDS: x tile [32][129] (pad +1: bank = (m+k)%32, conflict-free),
//      W half-tile [128][65] (64 k's at a time to stay under 64 KB static LDS).
// Thread tile: 2 nodes x 8 j.  j = jj*16 + jg so that for a fixed (k, jj) the
// 16 jg lanes hit 16 distinct banks and the 4 m-groups broadcast — no conflicts.
// ---------------------------------------------------------------------------
__global__ __launch_bounds__(256) void ln_gemm_kernel(
    const float* __restrict__ x, const float* __restrict__ W,
    const float* __restrict__ ln_w, const float* __restrict__ ln_b,
    float* __restrict__ h, int n)
{
    __shared__ float sx[32][129];   // 16512 B
    __shared__ float sw[128][65];   // 33280 B  -> ~49.8 KB total, 3 blocks/CU
    const int tid = threadIdx.x;
    const int n0  = blockIdx.x * 32;

    // ---- load x tile (coalesced) ----
    for (int i = tid; i < 32 * 128; i += 256) {
        int m = i >> 7, k = i & 127;
        int node = n0 + m;
        sx[m][k] = (node < n) ? x[(size_t)node * DIM + k] : 0.0f;
    }
    __syncthreads();

    // ---- LayerNorm: 8 threads per node (aligned 8-lane shfl groups) ----
    {
        int m = tid >> 3, sub = tid & 7;
        float s = 0.f, ss = 0.f;
        #pragma unroll
        for (int i = 0; i < 16; ++i) {
            float v = sx[m][sub * 16 + i];
            s += v; ss += v * v;
        }
        #pragma unroll
        for (int off = 1; off < 8; off <<= 1) {
            s  += __shfl_xor(s, off);
            ss += __shfl_xor(ss, off);
        }
        float mu   = s * (1.0f / 128.0f);
        float var  = ss * (1.0f / 128.0f) - mu * mu;
        float rstd = rsqrtf(var + LN_EPS);
        #pragma unroll
        for (int i = 0; i < 16; ++i) {
            int k = sub * 16 + i;
            float v = sx[m][k];
            sx[m][k] = (v - mu) * rstd * ln_w[k] + ln_b[k];
        }
    }
    __syncthreads();

    // ---- GEMM: thread = (mg, jg); computes nodes {2mg, 2mg+1} x j = jj*16+jg ----
    const int mg = tid >> 4;       // 0..15
    const int jg = tid & 15;       // 0..15
    const int m0 = mg * 2;
    float acc[2][8];
    #pragma unroll
    for (int a = 0; a < 2; ++a)
        #pragma unroll
        for (int jj = 0; jj < 8; ++jj) acc[a][jj] = 0.f;

    for (int kh = 0; kh < 128; kh += 64) {
        // stage W[:, kh:kh+64]: lanes cover one j-row of 64 k's -> 256B coalesced
        for (int i = tid; i < 128 * 64; i += 256) {
            int j = i >> 6, kk = i & 63;
            sw[j][kk] = W[j * DIM + kh + kk];
        }
        __syncthreads();
        for (int kk = 0; kk < 64; ++kk) {
            float xa = sx[m0][kh + kk];
            float xb = sx[m0 + 1][kh + kk];
            #pragma unroll
            for (int jj = 0; jj < 8; ++jj) {
                float wv = sw[jj * 16 + jg][kk];
                acc[0][jj] = fmaf(xa, wv, acc[0][jj]);
                acc[1][jj] = fmaf(xb, wv, acc[1][jj]);
            }
        }
        __syncthreads();
    }

    #pragma unroll
    for (int a = 0; a < 2; ++a) {
        int node = n0 + m0 + a;
        if (node < n) {
            #pragma unroll
            for (int jj = 0; jj < 8; ++jj)
                h[(size_t)node * DIM + jj * 16 + jg] = acc[a][jj];
        }
    }
}

// ---------------------------------------------------------------------------
// Degree = 1.0 (self loop) + segment_sum(edge_weight over targets)
// ---------------------------------------------------------------------------
__global__ __launch_bounds__(256) void deg_init_kernel(float* __restrict__ deg, int n) {
    int i = blockIdx.x * 256 + threadIdx.x;
    if (i < n) deg[i] = 1.0f;
}

__global__ __launch_bounds__(256) void deg_edge_kernel(
    const int* __restrict__ col, const float* __restrict__ ew,
    float* __restrict__ deg, int E)
{
    int e = blockIdx.x * 256 + threadIdx.x;
    if (e < E) atomicAdd(&deg[col[e]], ew[e]);
}

__global__ __launch_bounds__(256) void dinv_kernel(
    const float* __restrict__ deg, float* __restrict__ dinv, int n)
{
    int i = blockIdx.x * 256 + threadIdx.x;
    if (i < n) dinv[i] = rsqrtf(deg[i]);   // deg >= 1 always (self loop)
}

// ---------------------------------------------------------------------------
// Edge scatter: one wave per edge, 2 floats/lane (512 B coalesced gather),
// 128 fp32 atomicAdd into out[col].
// ---------------------------------------------------------------------------
__global__ __launch_bounds__(256) void scatter_kernel(
    const int* __restrict__ row, const int* __restrict__ col,
    const float* __restrict__ ew, const float* __restrict__ dinv,
    const float* __restrict__ h, float* __restrict__ out, int E)
{
    int wid  = (blockIdx.x * blockDim.x + threadIdx.x) >> 6;  // wave id = edge id
    int lane = threadIdx.x & 63;
    if (wid >= E) return;
    int r = row[wid], c = col[wid];
    float nrm = dinv[r] * ew[wid] * dinv[c];
    float2 hv = *(const float2*)(h + (size_t)r * DIM + lane * 2);
    float* op = out + (size_t)c * DIM + lane * 2;
    atomicAdd(op,     hv.x * nrm);
    atomicAdd(op + 1, hv.y * nrm);
}

// ---------------------------------------------------------------------------
// Finalize: out = gelu_exact(acc + dinv^2 * h (self loop) + b)
// ---------------------------------------------------------------------------
__global__ __launch_bounds__(256) void finalize_kernel(
    float* __restrict__ out, const float* __restrict__ h,
    const float* __restrict__ dinv, const float* __restrict__ b, int n)
{
    int i = blockIdx.x * 256 + threadIdx.x;
    if (i < n * DIM) {
        int node = i >> 7, d = i & 127;
        float di = dinv[node];
        float v  = out[i] + di * di * h[i] + b[d];
        out[i]   = 0.5f * v * (1.0f + erff(v * 0.70710678118654752f));
    }
}

extern "C" void kernel_launch(void* const* d_in, const int* in_sizes, int n_in,
                              void* d_out, int out_size, void* d_ws, size_t ws_size,
                              hipStream_t stream)
{
    const float* x    = (const float*)d_in[0];
    const int*   ei   = (const int*)d_in[1];   // [2][E], int32 per harness
    const float* ew   = (const float*)d_in[2];
    const float* W    = (const float*)d_in[3];
    const float* b    = (const float*)d_in[4];
    const float* ln_w = (const float*)d_in[5];
    const float* ln_b = (const float*)d_in[6];
    float* out = (float*)d_out;

    const int n = in_sizes[0] / DIM;
    const int E = in_sizes[2];
    const int* row  = ei;        // sources
    const int* colp = ei + E;    // targets

    // workspace layout: h [n*128] | deg [n] | dinv [n]   (~26 MB)
    float* h    = (float*)d_ws;
    float* deg  = h + (size_t)n * DIM;
    float* dinv = deg + n;

    hipMemsetAsync(d_out, 0, (size_t)out_size * sizeof(float), stream);

    ln_gemm_kernel<<<(n + 31) / 32, 256, 0, stream>>>(x, W, ln_w, ln_b, h, n);
    deg_init_kernel<<<(n + 255) / 256, 256, 0, stream>>>(deg, n);
    deg_edge_kernel<<<(E + 255) / 256, 256, 0, stream>>>(colp, ew, deg, E);
    dinv_kernel<<<(n + 255) / 256, 256, 0, stream>>>(deg, dinv, n);
    scatter_kernel<<<(E + 3) / 4, 256, 0, stream>>>(row, colp, ew, dinv, h, out, E);
    finalize_kernel<<<(n * DIM + 255) / 256, 256, 0, stream>>>(out, h, dinv, b, n);
}

// Round 2
// 335.821 us; speedup vs baseline: 2.5569x; 2.5569x over previous
//
#include <hip/hip_runtime.h>
#include <math.h>

#define DIM 128
#define LN_EPS 1e-5f

__device__ __forceinline__ float gelu_exact(float v) {
    return 0.5f * v * (1.0f + erff(v * 0.70710678118654752f));
}

// ---------------------------------------------------------------------------
// Kernel A: per-node LayerNorm fused with h = xn @ W^T  (unchanged from R1)
// ---------------------------------------------------------------------------
__global__ __launch_bounds__(256) void ln_gemm_kernel(
    const float* __restrict__ x, const float* __restrict__ W,
    const float* __restrict__ ln_w, const float* __restrict__ ln_b,
    float* __restrict__ h, int n)
{
    __shared__ float sx[32][129];
    __shared__ float sw[128][65];
    const int tid = threadIdx.x;
    const int n0  = blockIdx.x * 32;

    for (int i = tid; i < 32 * 128; i += 256) {
        int m = i >> 7, k = i & 127;
        int node = n0 + m;
        sx[m][k] = (node < n) ? x[(size_t)node * DIM + k] : 0.0f;
    }
    __syncthreads();

    {
        int m = tid >> 3, sub = tid & 7;
        float s = 0.f, ss = 0.f;
        #pragma unroll
        for (int i = 0; i < 16; ++i) {
            float v = sx[m][sub * 16 + i];
            s += v; ss += v * v;
        }
        #pragma unroll
        for (int off = 1; off < 8; off <<= 1) {
            s  += __shfl_xor(s, off);
            ss += __shfl_xor(ss, off);
        }
        float mu   = s * (1.0f / 128.0f);
        float var  = ss * (1.0f / 128.0f) - mu * mu;
        float rstd = rsqrtf(var + LN_EPS);
        #pragma unroll
        for (int i = 0; i < 16; ++i) {
            int k = sub * 16 + i;
            float v = sx[m][k];
            sx[m][k] = (v - mu) * rstd * ln_w[k] + ln_b[k];
        }
    }
    __syncthreads();

    const int mg = tid >> 4;
    const int jg = tid & 15;
    const int m0 = mg * 2;
    float acc[2][8];
    #pragma unroll
    for (int a = 0; a < 2; ++a)
        #pragma unroll
        for (int jj = 0; jj < 8; ++jj) acc[a][jj] = 0.f;

    for (int kh = 0; kh < 128; kh += 64) {
        for (int i = tid; i < 128 * 64; i += 256) {
            int j = i >> 6, kk = i & 63;
            sw[j][kk] = W[j * DIM + kh + kk];
        }
        __syncthreads();
        for (int kk = 0; kk < 64; ++kk) {
            float xa = sx[m0][kh + kk];
            float xb = sx[m0 + 1][kh + kk];
            #pragma unroll
            for (int jj = 0; jj < 8; ++jj) {
                float wv = sw[jj * 16 + jg][kk];
                acc[0][jj] = fmaf(xa, wv, acc[0][jj]);
                acc[1][jj] = fmaf(xb, wv, acc[1][jj]);
            }
        }
        __syncthreads();
    }

    #pragma unroll
    for (int a = 0; a < 2; ++a) {
        int node = n0 + m0 + a;
        if (node < n) {
            #pragma unroll
            for (int jj = 0; jj < 8; ++jj)
                h[(size_t)node * DIM + jj * 16 + jg] = acc[a][jj];
        }
    }
}

// ---------------------------------------------------------------------------
// CSR build: histogram -> scan -> fill
// ---------------------------------------------------------------------------
__global__ __launch_bounds__(256) void count_kernel(
    const int* __restrict__ col, const float* __restrict__ ew,
    int* __restrict__ cnt, float* __restrict__ deg, int E)
{
    int e = blockIdx.x * 256 + threadIdx.x;
    if (e < E) {
        int c = col[e];
        atomicAdd(&cnt[c], 1);
        atomicAdd(&deg[c], ew[e]);
    }
}

// scan A: per-block (1024 items) sums
__global__ __launch_bounds__(256) void scan_a_kernel(
    const int* __restrict__ cnt, int* __restrict__ bsum, int n)
{
    __shared__ int lds[256];
    int t = threadIdx.x, b = blockIdx.x;
    int base = b * 1024 + t * 4;
    int s = 0;
    if (base + 3 < n) {
        int4 c4 = *(const int4*)(cnt + base);
        s = c4.x + c4.y + c4.z + c4.w;
    } else {
        for (int i = 0; i < 4; ++i) if (base + i < n) s += cnt[base + i];
    }
    lds[t] = s; __syncthreads();
    for (int off = 128; off > 0; off >>= 1) {
        if (t < off) lds[t] += lds[t + off];
        __syncthreads();
    }
    if (t == 0) bsum[b] = lds[0];
}

// scan B: serial exclusive scan of block sums (nb ~ 49), writes offsets[n]=E
__global__ void scan_b_kernel(int* __restrict__ bsum, int* __restrict__ offsets,
                              int nb, int n)
{
    if (blockIdx.x == 0 && threadIdx.x == 0) {
        int run = 0;
        for (int i = 0; i < nb; ++i) { int v = bsum[i]; bsum[i] = run; run += v; }
        offsets[n] = run;
    }
}

// scan C: block-local exclusive scan + bsum offset; also dinv = rsqrt(deg+1)
__global__ __launch_bounds__(256) void scan_c_kernel(
    const int* __restrict__ cnt, const int* __restrict__ bsum,
    const float* __restrict__ deg,
    int* __restrict__ offsets, int* __restrict__ cursor,
    float* __restrict__ dinv, int n)
{
    __shared__ int lds[256];
    int t = threadIdx.x, b = blockIdx.x;
    int base = b * 1024 + t * 4;
    int v0 = 0, v1 = 0, v2 = 0, v3 = 0;
    bool full = (base + 3 < n);
    if (full) {
        int4 c4 = *(const int4*)(cnt + base);
        v0 = c4.x; v1 = c4.y; v2 = c4.z; v3 = c4.w;
    } else {
        if (base     < n) v0 = cnt[base];
        if (base + 1 < n) v1 = cnt[base + 1];
        if (base + 2 < n) v2 = cnt[base + 2];
        if (base + 3 < n) v3 = cnt[base + 3];
    }
    int s = v0 + v1 + v2 + v3;
    lds[t] = s; __syncthreads();
    int inc = s;
    for (int off = 1; off < 256; off <<= 1) {
        int add = (t >= off) ? lds[t - off] : 0;
        __syncthreads();
        inc += add;
        lds[t] = inc;
        __syncthreads();
    }
    int pre = bsum[b] + inc - s;  // exclusive prefix for this thread's 4 items
    int o0 = pre, o1 = pre + v0, o2 = o1 + v1, o3 = o2 + v2;
    if (full) {
        int4 o4 = make_int4(o0, o1, o2, o3);
        *(int4*)(offsets + base) = o4;
        *(int4*)(cursor  + base) = o4;
        float4 d4 = *(const float4*)(deg + base);
        float4 r4 = make_float4(rsqrtf(d4.x + 1.0f), rsqrtf(d4.y + 1.0f),
                                rsqrtf(d4.z + 1.0f), rsqrtf(d4.w + 1.0f));
        *(float4*)(dinv + base) = r4;
    } else {
        int oo[4] = {o0, o1, o2, o3};
        for (int i = 0; i < 4; ++i) if (base + i < n) {
            offsets[base + i] = oo[i];
            cursor[base + i]  = oo[i];
            dinv[base + i]    = rsqrtf(deg[base + i] + 1.0f);
        }
    }
}

__global__ __launch_bounds__(256) void fill_kernel(
    const int* __restrict__ row, const int* __restrict__ col,
    const float* __restrict__ ew, const float* __restrict__ dinv,
    int* __restrict__ cursor, int* __restrict__ src_s, float* __restrict__ nrm_s,
    int E)
{
    int e = blockIdx.x * 256 + threadIdx.x;
    if (e < E) {
        int r = row[e], c = col[e];
        int pos = atomicAdd(&cursor[c], 1);
        src_s[pos] = r;
        nrm_s[pos] = dinv[r] * ew[e] * dinv[c];
    }
}

// ---------------------------------------------------------------------------
// Pull gather: one wave per destination node; fused self-loop + bias + GELU.
// ---------------------------------------------------------------------------
__global__ __launch_bounds__(256) void gather_kernel(
    const int* __restrict__ offsets, const int* __restrict__ src_s,
    const float* __restrict__ nrm_s, const float* __restrict__ h,
    const float* __restrict__ dinv, const float* __restrict__ bias,
    float* __restrict__ out, int n)
{
    int wid  = (blockIdx.x * 256 + threadIdx.x) >> 6;
    int lane = threadIdx.x & 63;
    if (wid >= n) return;
    int beg = offsets[wid], end = offsets[wid + 1];
    float di = dinv[wid];
    float2 hv = *(const float2*)(h + (size_t)wid * DIM + lane * 2);
    float ax = di * di * hv.x, ay = di * di * hv.y;

    int j = beg;
    for (; j + 1 < end; j += 2) {
        int   s0 = src_s[j],  s1 = src_s[j + 1];
        float n0 = nrm_s[j],  n1 = nrm_s[j + 1];
        float2 a = *(const float2*)(h + (size_t)s0 * DIM + lane * 2);
        float2 c = *(const float2*)(h + (size_t)s1 * DIM + lane * 2);
        ax = fmaf(n0, a.x, ax); ay = fmaf(n0, a.y, ay);
        ax = fmaf(n1, c.x, ax); ay = fmaf(n1, c.y, ay);
    }
    if (j < end) {
        int s0 = src_s[j]; float n0 = nrm_s[j];
        float2 a = *(const float2*)(h + (size_t)s0 * DIM + lane * 2);
        ax = fmaf(n0, a.x, ax); ay = fmaf(n0, a.y, ay);
    }

    float vx = ax + bias[lane * 2];
    float vy = ay + bias[lane * 2 + 1];
    float2 o = make_float2(gelu_exact(vx), gelu_exact(vy));
    *(float2*)(out + (size_t)wid * DIM + lane * 2) = o;
}

// ---------------------------------------------------------------------------
// Fallback path (R1 atomic scatter) — used only if ws_size is too small.
// ---------------------------------------------------------------------------
__global__ __launch_bounds__(256) void deg_init_kernel(float* __restrict__ deg, int n) {
    int i = blockIdx.x * 256 + threadIdx.x;
    if (i < n) deg[i] = 1.0f;
}
__global__ __launch_bounds__(256) void deg_edge_kernel(
    const int* __restrict__ col, const float* __restrict__ ew,
    float* __restrict__ deg, int E)
{
    int e = blockIdx.x * 256 + threadIdx.x;
    if (e < E) atomicAdd(&deg[col[e]], ew[e]);
}
__global__ __launch_bounds__(256) void dinv_kernel(
    const float* __restrict__ deg, float* __restrict__ dinv, int n)
{
    int i = blockIdx.x * 256 + threadIdx.x;
    if (i < n) dinv[i] = rsqrtf(deg[i]);
}
__global__ __launch_bounds__(256) void scatter_kernel(
    const int* __restrict__ row, const int* __restrict__ col,
    const float* __restrict__ ew, const float* __restrict__ dinv,
    const float* __restrict__ h, float* __restrict__ out, int E)
{
    int wid  = (blockIdx.x * blockDim.x + threadIdx.x) >> 6;
    int lane = threadIdx.x & 63;
    if (wid >= E) return;
    int r = row[wid], c = col[wid];
    float nrm = dinv[r] * ew[wid] * dinv[c];
    float2 hv = *(const float2*)(h + (size_t)r * DIM + lane * 2);
    float* op = out + (size_t)c * DIM + lane * 2;
    atomicAdd(op,     hv.x * nrm);
    atomicAdd(op + 1, hv.y * nrm);
}
__global__ __launch_bounds__(256) void finalize_kernel(
    float* __restrict__ out, const float* __restrict__ h,
    const float* __restrict__ dinv, const float* __restrict__ b, int n)
{
    int i = blockIdx.x * 256 + threadIdx.x;
    if (i < n * DIM) {
        int node = i >> 7, d = i & 127;
        float di = dinv[node];
        float v  = out[i] + di * di * h[i] + b[d];
        out[i]   = gelu_exact(v);
    }
}

extern "C" void kernel_launch(void* const* d_in, const int* in_sizes, int n_in,
                              void* d_out, int out_size, void* d_ws, size_t ws_size,
                              hipStream_t stream)
{
    const float* x    = (const float*)d_in[0];
    const int*   ei   = (const int*)d_in[1];
    const float* ew   = (const float*)d_in[2];
    const float* W    = (const float*)d_in[3];
    const float* b    = (const float*)d_in[4];
    const float* ln_w = (const float*)d_in[5];
    const float* ln_b = (const float*)d_in[6];
    float* out = (float*)d_out;

    const int n = in_sizes[0] / DIM;
    const int E = in_sizes[2];
    const int* row  = ei;        // sources
    const int* colp = ei + E;    // targets

    const int NB = (n + 1023) / 1024;  // scan blocks

    // workspace layout
    float* h       = (float*)d_ws;                    // n*128
    float* deg     = h + (size_t)n * DIM;             // n
    int*   cnt     = (int*)(deg + n);                 // n
    float* dinv    = (float*)(cnt + n);               // n
    int*   offsets = (int*)(dinv + n);                // n+1
    int*   cursor  = offsets + n + 1;                 // n
    int*   bsum    = cursor + n;                      // NB (<=4096)
    int*   src_s   = bsum + 4096;                     // E
    float* nrm_s   = (float*)(src_s + E);             // E

    size_t need = ((size_t)n * DIM + 5 * (size_t)n + 1 + 4096) * 4 + (size_t)E * 8;

    if (ws_size >= need) {
        // ---- CSR pull path ----
        ln_gemm_kernel<<<(n + 31) / 32, 256, 0, stream>>>(x, W, ln_w, ln_b, h, n);
        hipMemsetAsync(deg, 0, (size_t)n * 2 * sizeof(float), stream); // deg + cnt
        count_kernel<<<(E + 255) / 256, 256, 0, stream>>>(colp, ew, cnt, deg, E);
        scan_a_kernel<<<NB, 256, 0, stream>>>(cnt, bsum, n);
        scan_b_kernel<<<1, 64, 0, stream>>>(bsum, offsets, NB, n);
        scan_c_kernel<<<NB, 256, 0, stream>>>(cnt, bsum, deg, offsets, cursor, dinv, n);
        fill_kernel<<<(E + 255) / 256, 256, 0, stream>>>(row, colp, ew, dinv, cursor,
                                                         src_s, nrm_s, E);
        gather_kernel<<<(n * 64 + 255) / 256, 256, 0, stream>>>(offsets, src_s, nrm_s,
                                                                h, dinv, b, out, n);
    } else {
        // ---- fallback: R1 atomic scatter ----
        hipMemsetAsync(d_out, 0, (size_t)out_size * sizeof(float), stream);
        ln_gemm_kernel<<<(n + 31) / 32, 256, 0, stream>>>(x, W, ln_w, ln_b, h, n);
        deg_init_kernel<<<(n + 255) / 256, 256, 0, stream>>>(deg, n);
        deg_edge_kernel<<<(E + 255) / 256, 256, 0, stream>>>(colp, ew, deg, E);
        dinv_kernel<<<(n + 255) / 256, 256, 0, stream>>>(deg, dinv, n);
        scatter_kernel<<<(E + 3) / 4, 256, 0, stream>>>(row, colp, ew, dinv, h, out, E);
        finalize_kernel<<<(n * DIM + 255) / 256, 256, 0, stream>>>(out, h, dinv, b, n);
    }
}

// Round 3
// 278.765 us; speedup vs baseline: 3.0802x; 1.2047x over previous
//
#include <hip/hip_runtime.h>
#include <math.h>

#define DIM 128
#define LN_EPS 1e-5f

__device__ __forceinline__ float gelu_exact(float v) {
    return 0.5f * v * (1.0f + erff(v * 0.70710678118654752f));
}

// ---------------------------------------------------------------------------
// Kernel A: per-node LayerNorm fused with h = xn @ W^T  (unchanged)
// ---------------------------------------------------------------------------
__global__ __launch_bounds__(256) void ln_gemm_kernel(
    const float* __restrict__ x, const float* __restrict__ W,
    const float* __restrict__ ln_w, const float* __restrict__ ln_b,
    float* __restrict__ h, int n)
{
    __shared__ float sx[32][129];
    __shared__ float sw[128][65];
    const int tid = threadIdx.x;
    const int n0  = blockIdx.x * 32;

    for (int i = tid; i < 32 * 128; i += 256) {
        int m = i >> 7, k = i & 127;
        int node = n0 + m;
        sx[m][k] = (node < n) ? x[(size_t)node * DIM + k] : 0.0f;
    }
    __syncthreads();

    {
        int m = tid >> 3, sub = tid & 7;
        float s = 0.f, ss = 0.f;
        #pragma unroll
        for (int i = 0; i < 16; ++i) {
            float v = sx[m][sub * 16 + i];
            s += v; ss += v * v;
        }
        #pragma unroll
        for (int off = 1; off < 8; off <<= 1) {
            s  += __shfl_xor(s, off);
            ss += __shfl_xor(ss, off);
        }
        float mu   = s * (1.0f / 128.0f);
        float var  = ss * (1.0f / 128.0f) - mu * mu;
        float rstd = rsqrtf(var + LN_EPS);
        #pragma unroll
        for (int i = 0; i < 16; ++i) {
            int k = sub * 16 + i;
            float v = sx[m][k];
            sx[m][k] = (v - mu) * rstd * ln_w[k] + ln_b[k];
        }
    }
    __syncthreads();

    const int mg = tid >> 4;
    const int jg = tid & 15;
    const int m0 = mg * 2;
    float acc[2][8];
    #pragma unroll
    for (int a = 0; a < 2; ++a)
        #pragma unroll
        for (int jj = 0; jj < 8; ++jj) acc[a][jj] = 0.f;

    for (int kh = 0; kh < 128; kh += 64) {
        for (int i = tid; i < 128 * 64; i += 256) {
            int j = i >> 6, kk = i & 63;
            sw[j][kk] = W[j * DIM + kh + kk];
        }
        __syncthreads();
        for (int kk = 0; kk < 64; ++kk) {
            float xa = sx[m0][kh + kk];
            float xb = sx[m0 + 1][kh + kk];
            #pragma unroll
            for (int jj = 0; jj < 8; ++jj) {
                float wv = sw[jj * 16 + jg][kk];
                acc[0][jj] = fmaf(xa, wv, acc[0][jj]);
                acc[1][jj] = fmaf(xb, wv, acc[1][jj]);
            }
        }
        __syncthreads();
    }

    #pragma unroll
    for (int a = 0; a < 2; ++a) {
        int node = n0 + m0 + a;
        if (node < n) {
            #pragma unroll
            for (int jj = 0; jj < 8; ++jj)
                h[(size_t)node * DIM + jj * 16 + jg] = acc[a][jj];
        }
    }
}

// ---------------------------------------------------------------------------
// rank pass: THE only atomic in the pipeline. rank[e] = arrival order at dest.
// ---------------------------------------------------------------------------
__global__ __launch_bounds__(256) void rank_kernel(
    const int* __restrict__ col, int* __restrict__ cnt,
    int* __restrict__ rank, int E)
{
    int e = blockIdx.x * 256 + threadIdx.x;
    if (e < E) rank[e] = atomicAdd(&cnt[col[e]], 1);
}

// ---------------------------------------------------------------------------
// Exclusive scan of cnt -> offsets (3-step, same as R2 minus cursor/dinv)
// ---------------------------------------------------------------------------
__global__ __launch_bounds__(256) void scan_a_kernel(
    const int* __restrict__ cnt, int* __restrict__ bsum, int n)
{
    __shared__ int lds[256];
    int t = threadIdx.x, b = blockIdx.x;
    int base = b * 1024 + t * 4;
    int s = 0;
    if (base + 3 < n) {
        int4 c4 = *(const int4*)(cnt + base);
        s = c4.x + c4.y + c4.z + c4.w;
    } else {
        for (int i = 0; i < 4; ++i) if (base + i < n) s += cnt[base + i];
    }
    lds[t] = s; __syncthreads();
    for (int off = 128; off > 0; off >>= 1) {
        if (t < off) lds[t] += lds[t + off];
        __syncthreads();
    }
    if (t == 0) bsum[b] = lds[0];
}

__global__ void scan_b_kernel(int* __restrict__ bsum, int* __restrict__ offsets,
                              int nb, int n)
{
    if (blockIdx.x == 0 && threadIdx.x == 0) {
        int run = 0;
        for (int i = 0; i < nb; ++i) { int v = bsum[i]; bsum[i] = run; run += v; }
        offsets[n] = run;
    }
}

__global__ __launch_bounds__(256) void scan_c_kernel(
    const int* __restrict__ cnt, const int* __restrict__ bsum,
    int* __restrict__ offsets, int n)
{
    __shared__ int lds[256];
    int t = threadIdx.x, b = blockIdx.x;
    int base = b * 1024 + t * 4;
    int v0 = 0, v1 = 0, v2 = 0, v3 = 0;
    bool full = (base + 3 < n);
    if (full) {
        int4 c4 = *(const int4*)(cnt + base);
        v0 = c4.x; v1 = c4.y; v2 = c4.z; v3 = c4.w;
    } else {
        if (base     < n) v0 = cnt[base];
        if (base + 1 < n) v1 = cnt[base + 1];
        if (base + 2 < n) v2 = cnt[base + 2];
        if (base + 3 < n) v3 = cnt[base + 3];
    }
    int s = v0 + v1 + v2 + v3;
    lds[t] = s; __syncthreads();
    int inc = s;
    for (int off = 1; off < 256; off <<= 1) {
        int add = (t >= off) ? lds[t - off] : 0;
        __syncthreads();
        inc += add;
        lds[t] = inc;
        __syncthreads();
    }
    int pre = bsum[b] + inc - s;
    int o0 = pre, o1 = pre + v0, o2 = o1 + v1, o3 = o2 + v2;
    if (full) {
        *(int4*)(offsets + base) = make_int4(o0, o1, o2, o3);
    } else {
        int oo[4] = {o0, o1, o2, o3};
        for (int i = 0; i < 4; ++i) if (base + i < n) offsets[base + i] = oo[i];
    }
}

// ---------------------------------------------------------------------------
// Atomic-free scatter: pos = offsets[col] + rank; packed (src, ew_bits).
// ---------------------------------------------------------------------------
__global__ __launch_bounds__(256) void scatter_fill_kernel(
    const int* __restrict__ row, const int* __restrict__ col,
    const float* __restrict__ ew, const int* __restrict__ rank,
    const int* __restrict__ offsets, int2* __restrict__ edge_s, int E)
{
    int e = blockIdx.x * 256 + threadIdx.x;
    if (e < E) {
        int c = col[e];
        int pos = offsets[c] + rank[e];
        edge_s[pos] = make_int2(row[e], __float_as_int(ew[e]));
    }
}

// ---------------------------------------------------------------------------
// deg = 1 + segment_sum(ew); dinv = rsqrt(deg). Thread per node; a wave's 64
// segments are contiguous in edge_s -> good line reuse.
// ---------------------------------------------------------------------------
__global__ __launch_bounds__(256) void deg_dinv_kernel(
    const int* __restrict__ offsets, const int2* __restrict__ edge_s,
    float* __restrict__ dinv, int n)
{
    int i = blockIdx.x * 256 + threadIdx.x;
    if (i < n) {
        int beg = offsets[i], end = offsets[i + 1];
        float s = 1.0f;
        for (int j = beg; j < end; ++j) s += __int_as_float(edge_s[j].y);
        dinv[i] = rsqrtf(s);
    }
}

// ---------------------------------------------------------------------------
// Pull gather: 2 nodes per wave (32 lanes x float4 each); trip count =
// max(degA,degB) not the sum. Fused self-loop + bias + exact GELU.
// ---------------------------------------------------------------------------
__global__ __launch_bounds__(256) void gather2_kernel(
    const int* __restrict__ offsets, const int2* __restrict__ edge_s,
    const float* __restrict__ dinv, const float* __restrict__ h,
    const float* __restrict__ bias, float* __restrict__ out, int n)
{
    int wave = (blockIdx.x * 256 + threadIdx.x) >> 6;
    int lane = threadIdx.x & 63;
    int half = lane >> 5;
    int sub  = lane & 31;
    int node = wave * 2 + half;
    if (node >= n) return;

    int beg = offsets[node], end = offsets[node + 1];
    float di = dinv[node];
    float4 hv = *(const float4*)(h + (size_t)node * DIM + sub * 4);
    float s2 = di * di;
    float4 acc = make_float4(s2 * hv.x, s2 * hv.y, s2 * hv.z, s2 * hv.w);

    int j = beg;
    for (; j + 1 < end; j += 2) {
        int2 e0 = edge_s[j], e1 = edge_s[j + 1];
        float n0 = dinv[e0.x] * __int_as_float(e0.y) * di;
        float n1 = dinv[e1.x] * __int_as_float(e1.y) * di;
        float4 a = *(const float4*)(h + (size_t)e0.x * DIM + sub * 4);
        float4 c = *(const float4*)(h + (size_t)e1.x * DIM + sub * 4);
        acc.x = fmaf(n0, a.x, acc.x); acc.y = fmaf(n0, a.y, acc.y);
        acc.z = fmaf(n0, a.z, acc.z); acc.w = fmaf(n0, a.w, acc.w);
        acc.x = fmaf(n1, c.x, acc.x); acc.y = fmaf(n1, c.y, acc.y);
        acc.z = fmaf(n1, c.z, acc.z); acc.w = fmaf(n1, c.w, acc.w);
    }
    if (j < end) {
        int2 e0 = edge_s[j];
        float n0 = dinv[e0.x] * __int_as_float(e0.y) * di;
        float4 a = *(const float4*)(h + (size_t)e0.x * DIM + sub * 4);
        acc.x = fmaf(n0, a.x, acc.x); acc.y = fmaf(n0, a.y, acc.y);
        acc.z = fmaf(n0, a.z, acc.z); acc.w = fmaf(n0, a.w, acc.w);
    }

    float4 bv = *(const float4*)(bias + sub * 4);
    float4 o;
    o.x = gelu_exact(acc.x + bv.x);
    o.y = gelu_exact(acc.y + bv.y);
    o.z = gelu_exact(acc.z + bv.z);
    o.w = gelu_exact(acc.w + bv.w);
    *(float4*)(out + (size_t)node * DIM + sub * 4) = o;
}

// ---------------------------------------------------------------------------
// Fallback path (R1 atomic scatter) — only if ws_size is too small.
// ---------------------------------------------------------------------------
__global__ __launch_bounds__(256) void deg_init_kernel(float* __restrict__ deg, int n) {
    int i = blockIdx.x * 256 + threadIdx.x;
    if (i < n) deg[i] = 1.0f;
}
__global__ __launch_bounds__(256) void deg_edge_kernel(
    const int* __restrict__ col, const float* __restrict__ ew,
    float* __restrict__ deg, int E)
{
    int e = blockIdx.x * 256 + threadIdx.x;
    if (e < E) atomicAdd(&deg[col[e]], ew[e]);
}
__global__ __launch_bounds__(256) void dinv_kernel(
    const float* __restrict__ deg, float* __restrict__ dinv, int n)
{
    int i = blockIdx.x * 256 + threadIdx.x;
    if (i < n) dinv[i] = rsqrtf(deg[i]);
}
__global__ __launch_bounds__(256) void scatter_kernel(
    const int* __restrict__ row, const int* __restrict__ col,
    const float* __restrict__ ew, const float* __restrict__ dinv,
    const float* __restrict__ h, float* __restrict__ out, int E)
{
    int wid  = (blockIdx.x * blockDim.x + threadIdx.x) >> 6;
    int lane = threadIdx.x & 63;
    if (wid >= E) return;
    int r = row[wid], c = col[wid];
    float nrm = dinv[r] * ew[wid] * dinv[c];
    float2 hv = *(const float2*)(h + (size_t)r * DIM + lane * 2);
    float* op = out + (size_t)c * DIM + lane * 2;
    atomicAdd(op,     hv.x * nrm);
    atomicAdd(op + 1, hv.y * nrm);
}
__global__ __launch_bounds__(256) void finalize_kernel(
    float* __restrict__ out, const float* __restrict__ h,
    const float* __restrict__ dinv, const float* __restrict__ b, int n)
{
    int i = blockIdx.x * 256 + threadIdx.x;
    if (i < n * DIM) {
        int node = i >> 7, d = i & 127;
        float di = dinv[node];
        float v  = out[i] + di * di * h[i] + b[d];
        out[i]   = gelu_exact(v);
    }
}

extern "C" void kernel_launch(void* const* d_in, const int* in_sizes, int n_in,
                              void* d_out, int out_size, void* d_ws, size_t ws_size,
                              hipStream_t stream)
{
    const float* x    = (const float*)d_in[0];
    const int*   ei   = (const int*)d_in[1];
    const float* ew   = (const float*)d_in[2];
    const float* W    = (const float*)d_in[3];
    const float* b    = (const float*)d_in[4];
    const float* ln_w = (const float*)d_in[5];
    const float* ln_b = (const float*)d_in[6];
    float* out = (float*)d_out;

    const int n = in_sizes[0] / DIM;
    const int E = in_sizes[2];
    const int* row  = ei;        // sources
    const int* colp = ei + E;    // targets

    const int NB = (n + 1023) / 1024;

    // workspace layout (8B-aligned chunks first)
    float* h       = (float*)d_ws;                       // n*128 f
    int2*  edge_s  = (int2*)(h + (size_t)n * DIM);       // E int2
    int*   cnt     = (int*)(edge_s + E);                 // n
    int*   rank    = cnt + n;                            // E
    int*   offsets = rank + E;                           // n+1
    int*   bsum    = offsets + n + 1;                    // 4096
    float* dinv    = (float*)(bsum + 4096);              // n

    size_t need = ((size_t)n * DIM + 3 * (size_t)n + 1 + 4096) * 4 + (size_t)E * 16;

    if (ws_size >= need) {
        ln_gemm_kernel<<<(n + 31) / 32, 256, 0, stream>>>(x, W, ln_w, ln_b, h, n);
        hipMemsetAsync(cnt, 0, (size_t)n * sizeof(int), stream);
        rank_kernel<<<(E + 255) / 256, 256, 0, stream>>>(colp, cnt, rank, E);
        scan_a_kernel<<<NB, 256, 0, stream>>>(cnt, bsum, n);
        scan_b_kernel<<<1, 64, 0, stream>>>(bsum, offsets, NB, n);
        scan_c_kernel<<<NB, 256, 0, stream>>>(cnt, bsum, offsets, n);
        scatter_fill_kernel<<<(E + 255) / 256, 256, 0, stream>>>(row, colp, ew, rank,
                                                                 offsets, edge_s, E);
        deg_dinv_kernel<<<(n + 255) / 256, 256, 0, stream>>>(offsets, edge_s, dinv, n);
        gather2_kernel<<<((n + 1) / 2 * 64 + 255) / 256, 256, 0, stream>>>(
            offsets, edge_s, dinv, h, b, out, n);
    } else {
        // fallback: R1 atomic scatter
        float* deg  = h + (size_t)n * DIM;
        float* dnv  = deg + n;
        hipMemsetAsync(d_out, 0, (size_t)out_size * sizeof(float), stream);
        ln_gemm_kernel<<<(n + 31) / 32, 256, 0, stream>>>(x, W, ln_w, ln_b, h, n);
        deg_init_kernel<<<(n + 255) / 256, 256, 0, stream>>>(deg, n);
        deg_edge_kernel<<<(E + 255) / 256, 256, 0, stream>>>(colp, ew, deg, E);
        dinv_kernel<<<(n + 255) / 256, 256, 0, stream>>>(deg, dnv, n);
        scatter_kernel<<<(E + 3) / 4, 256, 0, stream>>>(row, colp, ew, dnv, h, out, E);
        finalize_kernel<<<(n * DIM + 255) / 256, 256, 0, stream>>>(out, h, dnv, b, n);
    }
}

// Round 4
// 223.103 us; speedup vs baseline: 3.8487x; 1.2495x over previous
//
#include <hip/hip_runtime.h>
#include <math.h>

#define DIM 128
#define LN_EPS 1e-5f

__device__ __forceinline__ float gelu_exact(float v) {
    return 0.5f * v * (1.0f + erff(v * 0.70710678118654752f));
}
__device__ __forceinline__ float bf2f(unsigned short u) {
    return __uint_as_float(((unsigned)u) << 16);
}
__device__ __forceinline__ unsigned short f2bf(float f) {
    unsigned b = __float_as_uint(f);
    return (unsigned short)((b + 0x7FFF + ((b >> 16) & 1)) >> 16);  // RNE
}

// ---------------------------------------------------------------------------
// Fused kernel: blocks with blockIdx%3==2 do the rank atomics (2048 edges
// each, interleaved so they're resident from t=0 and the memory-side atomic
// drain overlaps the GEMM blocks' VALU work). Other blocks: LN + h = xn@W^T
// for a 64-node tile, h written as bf16.
// GEMM tiling: thread = 4 nodes x 8 j. Per kk: 4 b32 x-broadcasts (conflict-
// free) + 2 ds_read_b128 from transposed W tile -> 6 LDS instr / 32 FMA.
// ---------------------------------------------------------------------------
__global__ __launch_bounds__(256) void gemm_rank_kernel(
    const float* __restrict__ x, const float* __restrict__ W,
    const float* __restrict__ lnw, const float* __restrict__ lnb,
    unsigned short* __restrict__ h16,
    const int* __restrict__ col, int* __restrict__ cnt, int* __restrict__ rnk,
    int n, int E)
{
    const int tid = threadIdx.x;

    if ((int)(blockIdx.x % 3) == 2) {
        // ---------------- rank role: 1 atomic per edge ----------------
        int rb   = blockIdx.x / 3;
        int base = rb * 2048 + tid;
        #pragma unroll
        for (int it = 0; it < 8; ++it) {
            int e = base + it * 256;
            if (e < E) rnk[e] = atomicAdd(&cnt[col[e]], 1);
        }
        return;
    }

    // ---------------- GEMM role ----------------
    __shared__ float sx[64][132];    // 33.8 KB, stride 132: f4-aligned rows
    __shared__ float swT[32][132];   // 16.9 KB, W^T K-quarter
    const int gb = blockIdx.x - (blockIdx.x + 1) / 3;
    const int n0 = gb * 64;

    // stage x tile (float4, coalesced)
    const float4* x4 = (const float4*)(x + (size_t)n0 * DIM);
    for (int i = tid; i < 64 * 32; i += 256) {
        int m = i >> 5, k4 = i & 31;
        float4 v = (n0 + m < n) ? x4[m * 32 + k4] : make_float4(0.f, 0.f, 0.f, 0.f);
        *(float4*)&sx[m][k4 * 4] = v;
    }
    __syncthreads();

    // LayerNorm: 4 threads per node, float4 LDS traffic
    {
        int m = tid >> 2, sub = tid & 3;
        float s = 0.f, ss = 0.f;
        float4 v[8];
        #pragma unroll
        for (int i = 0; i < 8; ++i) {
            v[i] = *(const float4*)&sx[m][sub * 32 + i * 4];
            s  += v[i].x + v[i].y + v[i].z + v[i].w;
            ss += v[i].x * v[i].x + v[i].y * v[i].y + v[i].z * v[i].z + v[i].w * v[i].w;
        }
        s += __shfl_xor(s, 1); ss += __shfl_xor(ss, 1);
        s += __shfl_xor(s, 2); ss += __shfl_xor(ss, 2);
        float mu   = s * (1.0f / 128.0f);
        float var  = ss * (1.0f / 128.0f) - mu * mu;
        float rstd = rsqrtf(var + LN_EPS);
        #pragma unroll
        for (int i = 0; i < 8; ++i) {
            float4 lw = *(const float4*)(lnw + sub * 32 + i * 4);
            float4 lb = *(const float4*)(lnb + sub * 32 + i * 4);
            float4 o;
            o.x = (v[i].x - mu) * rstd * lw.x + lb.x;
            o.y = (v[i].y - mu) * rstd * lw.y + lb.y;
            o.z = (v[i].z - mu) * rstd * lw.z + lb.z;
            o.w = (v[i].w - mu) * rstd * lw.w + lb.w;
            *(float4*)&sx[m][sub * 32 + i * 4] = o;
        }
    }
    // (sx LN-writes are made visible by the __syncthreads below)

    const int mg = tid >> 4;   // 0..15
    const int jg = tid & 15;   // 0..15
    const int m0 = mg * 4;
    float acc[4][8];
    #pragma unroll
    for (int t = 0; t < 4; ++t)
        #pragma unroll
        for (int jj = 0; jj < 8; ++jj) acc[t][jj] = 0.f;

    for (int q = 0; q < 4; ++q) {
        // stage W^T quarter: swT[kk][j] = W[j][q*32+kk]
        for (int i = tid; i < 4096; i += 256) {
            int kk = i & 31, j = i >> 5;
            swT[kk][j] = W[j * DIM + q * 32 + kk];
        }
        __syncthreads();
        #pragma unroll 4
        for (int kk = 0; kk < 32; ++kk) {
            float4 w0 = *(const float4*)&swT[kk][jg * 8];
            float4 w1 = *(const float4*)&swT[kk][jg * 8 + 4];
            #pragma unroll
            for (int t = 0; t < 4; ++t) {
                float xv = sx[m0 + t][q * 32 + kk];
                acc[t][0] = fmaf(xv, w0.x, acc[t][0]);
                acc[t][1] = fmaf(xv, w0.y, acc[t][1]);
                acc[t][2] = fmaf(xv, w0.z, acc[t][2]);
                acc[t][3] = fmaf(xv, w0.w, acc[t][3]);
                acc[t][4] = fmaf(xv, w1.x, acc[t][4]);
                acc[t][5] = fmaf(xv, w1.y, acc[t][5]);
                acc[t][6] = fmaf(xv, w1.z, acc[t][6]);
                acc[t][7] = fmaf(xv, w1.w, acc[t][7]);
            }
        }
        __syncthreads();
    }

    // epilogue: h16[node][jg*8 .. jg*8+7] (bf16 RNE)
    #pragma unroll
    for (int t = 0; t < 4; ++t) {
        int node = n0 + m0 + t;
        if (node < n) {
            ushort4 p0, p1;
            p0.x = f2bf(acc[t][0]); p0.y = f2bf(acc[t][1]);
            p0.z = f2bf(acc[t][2]); p0.w = f2bf(acc[t][3]);
            p1.x = f2bf(acc[t][4]); p1.y = f2bf(acc[t][5]);
            p1.z = f2bf(acc[t][6]); p1.w = f2bf(acc[t][7]);
            unsigned short* dst = h16 + (size_t)node * DIM + jg * 8;
            *(ushort4*)dst       = p0;
            *(ushort4*)(dst + 4) = p1;
        }
    }
}

// ---------------------------------------------------------------------------
// Exclusive scan of cnt -> offsets (3-step)
// ---------------------------------------------------------------------------
__global__ __launch_bounds__(256) void scan_a_kernel(
    const int* __restrict__ cnt, int* __restrict__ bsum, int n)
{
    __shared__ int lds[256];
    int t = threadIdx.x, b = blockIdx.x;
    int base = b * 1024 + t * 4;
    int s = 0;
    if (base + 3 < n) {
        int4 c4 = *(const int4*)(cnt + base);
        s = c4.x + c4.y + c4.z + c4.w;
    } else {
        for (int i = 0; i < 4; ++i) if (base + i < n) s += cnt[base + i];
    }
    lds[t] = s; __syncthreads();
    for (int off = 128; off > 0; off >>= 1) {
        if (t < off) lds[t] += lds[t + off];
        __syncthreads();
    }
    if (t == 0) bsum[b] = lds[0];
}

__global__ void scan_b_kernel(int* __restrict__ bsum, int* __restrict__ offsets,
                              int nb, int n)
{
    if (blockIdx.x == 0 && threadIdx.x == 0) {
        int run = 0;
        for (int i = 0; i < nb; ++i) { int v = bsum[i]; bsum[i] = run; run += v; }
        offsets[n] = run;
    }
}

__global__ __launch_bounds__(256) void scan_c_kernel(
    const int* __restrict__ cnt, const int* __restrict__ bsum,
    int* __restrict__ offsets, int n)
{
    __shared__ int lds[256];
    int t = threadIdx.x, b = blockIdx.x;
    int base = b * 1024 + t * 4;
    int v0 = 0, v1 = 0, v2 = 0, v3 = 0;
    bool full = (base + 3 < n);
    if (full) {
        int4 c4 = *(const int4*)(cnt + base);
        v0 = c4.x; v1 = c4.y; v2 = c4.z; v3 = c4.w;
    } else {
        if (base     < n) v0 = cnt[base];
        if (base + 1 < n) v1 = cnt[base + 1];
        if (base + 2 < n) v2 = cnt[base + 2];
        if (base + 3 < n) v3 = cnt[base + 3];
    }
    int s = v0 + v1 + v2 + v3;
    lds[t] = s; __syncthreads();
    int inc = s;
    for (int off = 1; off < 256; off <<= 1) {
        int add = (t >= off) ? lds[t - off] : 0;
        __syncthreads();
        inc += add;
        lds[t] = inc;
        __syncthreads();
    }
    int pre = bsum[b] + inc - s;
    int o0 = pre, o1 = pre + v0, o2 = o1 + v1, o3 = o2 + v2;
    if (full) {
        *(int4*)(offsets + base) = make_int4(o0, o1, o2, o3);
    } else {
        int oo[4] = {o0, o1, o2, o3};
        for (int i = 0; i < 4; ++i) if (base + i < n) offsets[base + i] = oo[i];
    }
}

// ---------------------------------------------------------------------------
// Atomic-free fill: pos = offsets[col] + rank
// ---------------------------------------------------------------------------
__global__ __launch_bounds__(256) void scatter_fill_kernel(
    const int* __restrict__ row, const int* __restrict__ col,
    const float* __restrict__ ew, const int* __restrict__ rank,
    const int* __restrict__ offsets, int2* __restrict__ edge_s, int E)
{
    int e = blockIdx.x * 256 + threadIdx.x;
    if (e < E) {
        int c = col[e];
        int pos = offsets[c] + rank[e];
        edge_s[pos] = make_int2(row[e], __float_as_int(ew[e]));
    }
}

__global__ __launch_bounds__(256) void deg_dinv_kernel(
    const int* __restrict__ offsets, const int2* __restrict__ edge_s,
    float* __restrict__ dinv, int n)
{
    int i = blockIdx.x * 256 + threadIdx.x;
    if (i < n) {
        int beg = offsets[i], end = offsets[i + 1];
        float s = 1.0f;
        for (int j = beg; j < end; ++j) s += __int_as_float(edge_s[j].y);
        dinv[i] = rsqrtf(s);
    }
}

// ---------------------------------------------------------------------------
// Pull gather on bf16 h: 2 nodes/wave, 32 lanes x 4 dims (8 B loads).
// Fused self-loop + bias + exact GELU. fp32 accumulate.
// ---------------------------------------------------------------------------
__global__ __launch_bounds__(256) void gather2_kernel(
    const int* __restrict__ offsets, const int2* __restrict__ edge_s,
    const float* __restrict__ dinv, const unsigned short* __restrict__ h16,
    const float* __restrict__ bias, float* __restrict__ out, int n)
{
    int wave = (blockIdx.x * 256 + threadIdx.x) >> 6;
    int lane = threadIdx.x & 63;
    int half = lane >> 5;
    int sub  = lane & 31;
    int node = wave * 2 + half;
    if (node >= n) return;

    int beg = offsets[node], end = offsets[node + 1];
    float di = dinv[node];
    ushort4 sv = *(const ushort4*)(h16 + (size_t)node * DIM + sub * 4);
    float s2 = di * di;
    float4 acc = make_float4(s2 * bf2f(sv.x), s2 * bf2f(sv.y),
                             s2 * bf2f(sv.z), s2 * bf2f(sv.w));

    int j = beg;
    for (; j + 1 < end; j += 2) {
        int2 e0 = edge_s[j], e1 = edge_s[j + 1];
        float n0 = dinv[e0.x] * __int_as_float(e0.y) * di;
        float n1 = dinv[e1.x] * __int_as_float(e1.y) * di;
        ushort4 a = *(const ushort4*)(h16 + (size_t)e0.x * DIM + sub * 4);
        ushort4 c = *(const ushort4*)(h16 + (size_t)e1.x * DIM + sub * 4);
        acc.x = fmaf(n0, bf2f(a.x), acc.x); acc.y = fmaf(n0, bf2f(a.y), acc.y);
        acc.z = fmaf(n0, bf2f(a.z), acc.z); acc.w = fmaf(n0, bf2f(a.w), acc.w);
        acc.x = fmaf(n1, bf2f(c.x), acc.x); acc.y = fmaf(n1, bf2f(c.y), acc.y);
        acc.z = fmaf(n1, bf2f(c.z), acc.z); acc.w = fmaf(n1, bf2f(c.w), acc.w);
    }
    if (j < end) {
        int2 e0 = edge_s[j];
        float n0 = dinv[e0.x] * __int_as_float(e0.y) * di;
        ushort4 a = *(const ushort4*)(h16 + (size_t)e0.x * DIM + sub * 4);
        acc.x = fmaf(n0, bf2f(a.x), acc.x); acc.y = fmaf(n0, bf2f(a.y), acc.y);
        acc.z = fmaf(n0, bf2f(a.z), acc.z); acc.w = fmaf(n0, bf2f(a.w), acc.w);
    }

    float4 bv = *(const float4*)(bias + sub * 4);
    float4 o;
    o.x = gelu_exact(acc.x + bv.x);
    o.y = gelu_exact(acc.y + bv.y);
    o.z = gelu_exact(acc.z + bv.z);
    o.w = gelu_exact(acc.w + bv.w);
    *(float4*)(out + (size_t)node * DIM + sub * 4) = o;
}

extern "C" void kernel_launch(void* const* d_in, const int* in_sizes, int n_in,
                              void* d_out, int out_size, void* d_ws, size_t ws_size,
                              hipStream_t stream)
{
    const float* x    = (const float*)d_in[0];
    const int*   ei   = (const int*)d_in[1];
    const float* ew   = (const float*)d_in[2];
    const float* W    = (const float*)d_in[3];
    const float* b    = (const float*)d_in[4];
    const float* ln_w = (const float*)d_in[5];
    const float* ln_b = (const float*)d_in[6];
    float* out = (float*)d_out;

    const int n = in_sizes[0] / DIM;
    const int E = in_sizes[2];
    const int* row  = ei;        // sources
    const int* colp = ei + E;    // targets

    const int NB = (n + 1023) / 1024;

    // workspace layout (8B-aligned first)
    int2*           edge_s  = (int2*)d_ws;                           // E
    unsigned short* h16     = (unsigned short*)(edge_s + E);         // n*128
    int*            cnt     = (int*)(h16 + (size_t)n * DIM);         // n
    int*            rank    = cnt + n;                               // E
    int*            offsets = rank + E;                              // n+1
    int*            bsum    = offsets + n + 1;                       // 4096
    float*          dinv    = (float*)(bsum + 4096);                 // n
    // total ~23 MB (R3's 39 MB layout fit, so this fits)

    const int GB = (n + 63) / 64;       // gemm blocks (782)
    const int RB = (E + 2047) / 2048;   // rank blocks (391)
    int T = GB + RB;
    while (T / 3 < RB || T - T / 3 < GB) ++T;  // interleave coverage (guarded)

    hipMemsetAsync(cnt, 0, (size_t)n * sizeof(int), stream);
    gemm_rank_kernel<<<T, 256, 0, stream>>>(x, W, ln_w, ln_b, h16,
                                            colp, cnt, rank, n, E);
    scan_a_kernel<<<NB, 256, 0, stream>>>(cnt, bsum, n);
    scan_b_kernel<<<1, 64, 0, stream>>>(bsum, offsets, NB, n);
    scan_c_kernel<<<NB, 256, 0, stream>>>(cnt, bsum, offsets, n);
    scatter_fill_kernel<<<(E + 255) / 256, 256, 0, stream>>>(row, colp, ew, rank,
                                                             offsets, edge_s, E);
    deg_dinv_kernel<<<(n + 255) / 256, 256, 0, stream>>>(offsets, edge_s, dinv, n);
    gather2_kernel<<<((n + 1) / 2 * 64 + 255) / 256, 256, 0, stream>>>(
        offsets, edge_s, dinv, h16, b, out, n);
}

// Round 5
// 191.427 us; speedup vs baseline: 4.4855x; 1.1655x over previous
//
#include <hip/hip_runtime.h>
#include <math.h>

#define DIM 128
#define LN_EPS 1e-5f

typedef __attribute__((ext_vector_type(8))) short short8;   // 8 bf16 = 4 VGPR
typedef __attribute__((ext_vector_type(4))) float floatx4;

__device__ __forceinline__ float gelu_exact(float v) {
    return 0.5f * v * (1.0f + erff(v * 0.70710678118654752f));
}
__device__ __forceinline__ float bf2f(unsigned short u) {
    return __uint_as_float(((unsigned)u) << 16);
}
__device__ __forceinline__ short f2bf(float f) {
    unsigned b = __float_as_uint(f);
    return (short)((b + 0x7FFF + ((b >> 16) & 1)) >> 16);  // RNE
}

// ---------------------------------------------------------------------------
// Fused: rank-role blocks (blockIdx%3==2) drain the per-edge atomic on the
// memory side while gemm-role blocks do LN + h = xn@W^T via bf16 MFMA.
//
// MFMA plan (16x16x32_bf16): block = 64 nodes, 4 waves; wave w owns m-tile
// [w*16, w*16+16). LDS holds A and B in FRAGMENT order so every ds_read_b128
// is lane-consecutive (conflict-free):
//   A slot = w*256 + kq*64 + lane   holds xn[m=lane&15][k=kq*32+(lane>>4)*8+j]
//   B slot = jt*256 + kq*64 + lane  holds W[n=jt*16+(lane&15)][k=kq*32+(lane>>4)*8+j]
// Per wave: 4 A-frag + 32 B-frag ds_read_b128 feeding 32 MFMAs.
// ---------------------------------------------------------------------------
__global__ __launch_bounds__(256) void gemm_rank_kernel(
    const float* __restrict__ x, const float* __restrict__ W,
    const float* __restrict__ lnw, const float* __restrict__ lnb,
    unsigned short* __restrict__ h16,
    const int* __restrict__ col, int* __restrict__ cnt, int* __restrict__ rnk,
    int n, int E)
{
    const int tid = threadIdx.x;

    if ((int)(blockIdx.x % 3) == 2) {
        // ---------------- rank role: 1 atomic per edge ----------------
        int rb   = blockIdx.x / 3;
        int base = rb * 2048 + tid;
        #pragma unroll
        for (int it = 0; it < 8; ++it) {
            int e = base + it * 256;
            if (e < E) rnk[e] = atomicAdd(&cnt[col[e]], 1);
        }
        return;
    }

    __shared__ short swb[2048 * 8];   // 32 KB: W bf16 fragments
    __shared__ short axb[1024 * 8];   // 16 KB: xn bf16 fragments

    const int gb = blockIdx.x - (blockIdx.x + 1) / 3;
    const int n0 = gb * 64;

    // ---- stage W fragments (8 slots/thread). Slot c is lane-linear on the
    // read side; global W reads are strided (L1/L2-resident, once per block).
    for (int c = tid; c < 2048; c += 256) {
        int nrow = ((c >> 8) << 4) | (c & 15);                 // jt*16 + nloc
        int kb   = (((c >> 6) & 3) << 5) + (((c >> 4) & 3) << 3); // kq*32+quad*8
        const float* wp = W + nrow * DIM + kb;
        float4 w0 = *(const float4*)wp;
        float4 w1 = *(const float4*)(wp + 4);
        short8 p;
        p[0] = f2bf(w0.x); p[1] = f2bf(w0.y); p[2] = f2bf(w0.z); p[3] = f2bf(w0.w);
        p[4] = f2bf(w1.x); p[5] = f2bf(w1.y); p[6] = f2bf(w1.z); p[7] = f2bf(w1.w);
        *(short8*)&swb[c * 8] = p;
    }

    // ---- LayerNorm straight from global (x read once), 4 threads/node ----
    {
        int m = tid >> 2, sub = tid & 3;
        int node = n0 + m;
        bool valid = (node < n);
        const float4* xp = (const float4*)(x + (size_t)node * DIM + sub * 32);
        float4 v[8];
        float s = 0.f, ss = 0.f;
        #pragma unroll
        for (int i = 0; i < 8; ++i) {
            v[i] = valid ? xp[i] : make_float4(0.f, 0.f, 0.f, 0.f);
            s  += v[i].x + v[i].y + v[i].z + v[i].w;
            ss += v[i].x * v[i].x + v[i].y * v[i].y + v[i].z * v[i].z + v[i].w * v[i].w;
        }
        s += __shfl_xor(s, 1); ss += __shfl_xor(ss, 1);
        s += __shfl_xor(s, 2); ss += __shfl_xor(ss, 2);
        float mu   = s * (1.0f / 128.0f);
        float var  = ss * (1.0f / 128.0f) - mu * mu;
        float rstd = rsqrtf(var + LN_EPS);

        int mt = m >> 4, mloc = m & 15;
        #pragma unroll
        for (int quad = 0; quad < 4; ++quad) {
            float4 a = v[2 * quad], c4 = v[2 * quad + 1];
            const float4* lw = (const float4*)(lnw + sub * 32 + quad * 8);
            const float4* lb = (const float4*)(lnb + sub * 32 + quad * 8);
            float4 lw0 = lw[0], lw1 = lw[1], lb0 = lb[0], lb1 = lb[1];
            short8 p;
            p[0] = f2bf((a.x  - mu) * rstd * lw0.x + lb0.x);
            p[1] = f2bf((a.y  - mu) * rstd * lw0.y + lb0.y);
            p[2] = f2bf((a.z  - mu) * rstd * lw0.z + lb0.z);
            p[3] = f2bf((a.w  - mu) * rstd * lw0.w + lb0.w);
            p[4] = f2bf((c4.x - mu) * rstd * lw1.x + lb1.x);
            p[5] = f2bf((c4.y - mu) * rstd * lw1.y + lb1.y);
            p[6] = f2bf((c4.z - mu) * rstd * lw1.z + lb1.z);
            p[7] = f2bf((c4.w - mu) * rstd * lw1.w + lb1.w);
            int slot = mt * 256 + sub * 64 + quad * 16 + mloc;
            *(short8*)&axb[slot * 8] = p;
        }
    }
    __syncthreads();

    // ---- MFMA compute: wave w -> m-tile w, all 8 j-tiles ----
    const int w    = tid >> 6;
    const int lane = tid & 63;

    short8 afrag[4];
    #pragma unroll
    for (int kq = 0; kq < 4; ++kq)
        afrag[kq] = *(const short8*)&axb[(w * 256 + kq * 64 + lane) * 8];

    floatx4 acc[8];
    #pragma unroll
    for (int jt = 0; jt < 8; ++jt) acc[jt] = (floatx4){0.f, 0.f, 0.f, 0.f};

    #pragma unroll
    for (int jt = 0; jt < 8; ++jt) {
        #pragma unroll
        for (int kq = 0; kq < 4; ++kq) {
            short8 bfrag = *(const short8*)&swb[(jt * 256 + kq * 64 + lane) * 8];
            acc[jt] = __builtin_amdgcn_mfma_f32_16x16x32_bf16(afrag[kq], bfrag,
                                                              acc[jt], 0, 0, 0);
        }
    }

    // ---- epilogue: D row = quad*4+reg, col = jt*16 + (lane&15) ----
    const int quad = lane >> 4, nl = lane & 15;
    #pragma unroll
    for (int jt = 0; jt < 8; ++jt) {
        #pragma unroll
        for (int r = 0; r < 4; ++r) {
            int rnode = n0 + w * 16 + quad * 4 + r;
            if (rnode < n)
                h16[(size_t)rnode * DIM + jt * 16 + nl] = (unsigned short)f2bf(acc[jt][r]);
        }
    }
}

// ---------------------------------------------------------------------------
// Scan step A: per-1024-chunk sums
// ---------------------------------------------------------------------------
__global__ __launch_bounds__(256) void scan_a_kernel(
    const int* __restrict__ cnt, int* __restrict__ bsum, int n)
{
    __shared__ int lds[256];
    int t = threadIdx.x, b = blockIdx.x;
    int base = b * 1024 + t * 4;
    int s = 0;
    if (base + 3 < n) {
        int4 c4 = *(const int4*)(cnt + base);
        s = c4.x + c4.y + c4.z + c4.w;
    } else {
        for (int i = 0; i < 4; ++i) if (base + i < n) s += cnt[base + i];
    }
    lds[t] = s; __syncthreads();
    for (int off = 128; off > 0; off >>= 1) {
        if (t < off) lds[t] += lds[t + off];
        __syncthreads();
    }
    if (t == 0) bsum[b] = lds[0];
}

// ---------------------------------------------------------------------------
// Scan step BC (merged): each block serially folds bsum[0..b) (nb ~ 49, L2
// broadcast) then does the block-local exclusive scan.
// ---------------------------------------------------------------------------
__global__ __launch_bounds__(256) void scan_bc_kernel(
    const int* __restrict__ cnt, const int* __restrict__ bsum,
    int* __restrict__ offsets, int nb, int n)
{
    __shared__ int lds[256];
    int t = threadIdx.x, b = blockIdx.x;
    int pre0 = 0, total = 0;
    for (int i = 0; i < nb; ++i) {
        int v = bsum[i];
        if (i < b) pre0 += v;
        total += v;
    }
    int base = b * 1024 + t * 4;
    int v0 = 0, v1 = 0, v2 = 0, v3 = 0;
    bool full = (base + 3 < n);
    if (full) {
        int4 c4 = *(const int4*)(cnt + base);
        v0 = c4.x; v1 = c4.y; v2 = c4.z; v3 = c4.w;
    } else {
        if (base     < n) v0 = cnt[base];
        if (base + 1 < n) v1 = cnt[base + 1];
        if (base + 2 < n) v2 = cnt[base + 2];
        if (base + 3 < n) v3 = cnt[base + 3];
    }
    int s = v0 + v1 + v2 + v3;
    lds[t] = s; __syncthreads();
    int inc = s;
    for (int off = 1; off < 256; off <<= 1) {
        int add = (t >= off) ? lds[t - off] : 0;
        __syncthreads();
        inc += add;
        lds[t] = inc;
        __syncthreads();
    }
    int pre = pre0 + inc - s;
    int o0 = pre, o1 = pre + v0, o2 = o1 + v1, o3 = o2 + v2;
    if (full) {
        *(int4*)(offsets + base) = make_int4(o0, o1, o2, o3);
    } else {
        int oo[4] = {o0, o1, o2, o3};
        for (int i = 0; i < 4; ++i) if (base + i < n) offsets[base + i] = oo[i];
    }
    if (b == 0 && t == 0) offsets[n] = total;
}

// ---------------------------------------------------------------------------
// Atomic-free fill: pos = offsets[col] + rank
// ---------------------------------------------------------------------------
__global__ __launch_bounds__(256) void scatter_fill_kernel(
    const int* __restrict__ row, const int* __restrict__ col,
    const float* __restrict__ ew, const int* __restrict__ rank,
    const int* __restrict__ offsets, int2* __restrict__ edge_s, int E)
{
    int e = blockIdx.x * 256 + threadIdx.x;
    if (e < E) {
        int c = col[e];
        int pos = offsets[c] + rank[e];
        edge_s[pos] = make_int2(row[e], __float_as_int(ew[e]));
    }
}

__global__ __launch_bounds__(256) void deg_dinv_kernel(
    const int* __restrict__ offsets, const int2* __restrict__ edge_s,
    float* __restrict__ dinv, int n)
{
    int i = blockIdx.x * 256 + threadIdx.x;
    if (i < n) {
        int beg = offsets[i], end = offsets[i + 1];
        float s = 1.0f;
        for (int j = beg; j < end; ++j) s += __int_as_float(edge_s[j].y);
        dinv[i] = rsqrtf(s);
    }
}

// ---------------------------------------------------------------------------
// Pull gather: 4 nodes/wave, 16 lanes x 8 dims, 16 B h16 loads.
// Fused self-loop + bias + exact GELU. fp32 accumulate.
// ---------------------------------------------------------------------------
__global__ __launch_bounds__(256) void gather4_kernel(
    const int* __restrict__ offsets, const int2* __restrict__ edge_s,
    const float* __restrict__ dinv, const unsigned short* __restrict__ h16,
    const float* __restrict__ bias, float* __restrict__ out, int n)
{
    int wave = (blockIdx.x * 256 + threadIdx.x) >> 6;
    int lane = threadIdx.x & 63;
    int grp  = lane >> 4;
    int sub  = lane & 15;
    int node = wave * 4 + grp;
    if (node >= n) return;

    int beg = offsets[node], end = offsets[node + 1];
    float di = dinv[node];
    short8 sv = *(const short8*)(h16 + (size_t)node * DIM + sub * 8);
    float s2 = di * di;
    float acc[8];
    #pragma unroll
    for (int d = 0; d < 8; ++d) acc[d] = s2 * bf2f((unsigned short)sv[d]);

    int j = beg;
    for (; j + 1 < end; j += 2) {
        int2 e0 = edge_s[j], e1 = edge_s[j + 1];
        float n0 = dinv[e0.x] * __int_as_float(e0.y) * di;
        float n1 = dinv[e1.x] * __int_as_float(e1.y) * di;
        short8 a = *(const short8*)(h16 + (size_t)e0.x * DIM + sub * 8);
        short8 c = *(const short8*)(h16 + (size_t)e1.x * DIM + sub * 8);
        #pragma unroll
        for (int d = 0; d < 8; ++d) acc[d] = fmaf(n0, bf2f((unsigned short)a[d]), acc[d]);
        #pragma unroll
        for (int d = 0; d < 8; ++d) acc[d] = fmaf(n1, bf2f((unsigned short)c[d]), acc[d]);
    }
    if (j < end) {
        int2 e0 = edge_s[j];
        float n0 = dinv[e0.x] * __int_as_float(e0.y) * di;
        short8 a = *(const short8*)(h16 + (size_t)e0.x * DIM + sub * 8);
        #pragma unroll
        for (int d = 0; d < 8; ++d) acc[d] = fmaf(n0, bf2f((unsigned short)a[d]), acc[d]);
    }

    float4 b0 = *(const float4*)(bias + sub * 8);
    float4 b1 = *(const float4*)(bias + sub * 8 + 4);
    float4 o0, o1;
    o0.x = gelu_exact(acc[0] + b0.x); o0.y = gelu_exact(acc[1] + b0.y);
    o0.z = gelu_exact(acc[2] + b0.z); o0.w = gelu_exact(acc[3] + b0.w);
    o1.x = gelu_exact(acc[4] + b1.x); o1.y = gelu_exact(acc[5] + b1.y);
    o1.z = gelu_exact(acc[6] + b1.z); o1.w = gelu_exact(acc[7] + b1.w);
    float* op = out + (size_t)node * DIM + sub * 8;
    *(float4*)op       = o0;
    *(float4*)(op + 4) = o1;
}

extern "C" void kernel_launch(void* const* d_in, const int* in_sizes, int n_in,
                              void* d_out, int out_size, void* d_ws, size_t ws_size,
                              hipStream_t stream)
{
    const float* x    = (const float*)d_in[0];
    const int*   ei   = (const int*)d_in[1];
    const float* ew   = (const float*)d_in[2];
    const float* W    = (const float*)d_in[3];
    const float* b    = (const float*)d_in[4];
    const float* ln_w = (const float*)d_in[5];
    const float* ln_b = (const float*)d_in[6];
    float* out = (float*)d_out;

    const int n = in_sizes[0] / DIM;
    const int E = in_sizes[2];
    const int* row  = ei;        // sources
    const int* colp = ei + E;    // targets

    const int NB = (n + 1023) / 1024;

    // workspace layout (8B-aligned first)
    int2*           edge_s  = (int2*)d_ws;                           // E
    unsigned short* h16     = (unsigned short*)(edge_s + E);         // n*128
    int*            cnt     = (int*)(h16 + (size_t)n * DIM);         // n
    int*            rank    = cnt + n;                               // E
    int*            offsets = rank + E;                              // n+1
    int*            bsum    = offsets + n + 1;                       // 4096
    float*          dinv    = (float*)(bsum + 4096);                 // n

    const int GB = (n + 63) / 64;       // gemm blocks
    const int RB = (E + 2047) / 2048;   // rank blocks
    int T = GB + RB;
    while (T / 3 < RB || T - T / 3 < GB) ++T;

    hipMemsetAsync(cnt, 0, (size_t)n * sizeof(int), stream);
    gemm_rank_kernel<<<T, 256, 0, stream>>>(x, W, ln_w, ln_b, h16,
                                            colp, cnt, rank, n, E);
    scan_a_kernel<<<NB, 256, 0, stream>>>(cnt, bsum, n);
    scan_bc_kernel<<<NB, 256, 0, stream>>>(cnt, bsum, offsets, NB, n);
    scatter_fill_kernel<<<(E + 255) / 256, 256, 0, stream>>>(row, colp, ew, rank,
                                                             offsets, edge_s, E);
    deg_dinv_kernel<<<(n + 255) / 256, 256, 0, stream>>>(offsets, edge_s, dinv, n);
    {
        int waves = (n + 3) / 4;
        int blocks = (waves + 3) / 4;
        gather4_kernel<<<blocks, 256, 0, stream>>>(offsets, edge_s, dinv, h16, b, out, n);
    }
}